// Round 6
// baseline (457.609 us; speedup 1.0000x reference)
//
#include <hip/hip_runtime.h>
#include <stdint.h>

// ---------------------------------------------------------------------------
// VQ-VAE layer, all-bf16 MFMA pipeline.
// R13 -> R14: setprio theory refuted (R13 main loop ~= R11 with it). Stall
// model now closes: the two same-wv waves of the two co-resident blocks run
// an IDENTICAL loop launched simultaneously -> phase-locked; stage phase
// (LDS port ~1100cy) and MFMA phase (1242cy) ADD instead of overlap ->
// 2950cy/chunk. R14:
//  1. vq_dist: phase-stagger probe -- delay blocks by ~half a chunk period
//     at entry (s_sleep loop, hedged on blockIdx bits 8/3 for the unknown
//     co-residency pairing). Anti-phase waves hide each other's stage phase.
//  2. GEMM: BK 64->128. K=1024 paid 16x(vmcnt(0)+2-barrier) drains -- the
//     known m97-structure stall; halve the K-steps. LDS 32->64KB still fits
//     2 blocks/CU. Same staging instr count, same FP accumulation order.
// ---------------------------------------------------------------------------

typedef short bf16x8 __attribute__((ext_vector_type(8)));
typedef float f32x4 __attribute__((ext_vector_type(4)));

__device__ __forceinline__ void gl2lds16(const void* g, void* l) {
  __builtin_amdgcn_global_load_lds(
      (const __attribute__((address_space(1))) void*)g,
      (__attribute__((address_space(3))) void*)l, 16, 0, 0);
}

__device__ __forceinline__ float bf2f(unsigned short u) {
  return __uint_as_float(((unsigned)u) << 16);
}
__device__ __forceinline__ unsigned short f2bf(float f) {
  unsigned x = __float_as_uint(f);
  unsigned r = (x + 0x7fffu + ((x >> 16) & 1u)) >> 16;  // RNE
  return (unsigned short)r;
}
__device__ __forceinline__ unsigned long long packScore(float s, int code) {
  unsigned u = __float_as_uint(s);
  u = (u & 0x80000000u) ? ~u : (u | 0x80000000u);  // monotone map f32 -> u32
  return ((unsigned long long)u << 32) | (unsigned)code;
}
__device__ __forceinline__ unsigned long long shflxor_u64(unsigned long long v, int m) {
  union { unsigned long long u; int i[2]; } a;
  a.u = v;
  a.i[0] = __shfl_xor(a.i[0], m);
  a.i[1] = __shfl_xor(a.i[1], m);
  return a.u;
}

// ---------------------------------------------------------------------------
// cast fp32 -> bf16 (vectorized, n4 = count/4)
__global__ __launch_bounds__(256)
void cast_bf16(const float* __restrict__ X, unsigned short* __restrict__ Y, int n4) {
  int i = blockIdx.x * 256 + threadIdx.x;
  if (i < n4) {
    float4 v = ((const float4*)X)[i];
    ushort4 o = make_ushort4(f2bf(v.x), f2bf(v.y), f2bf(v.z), f2bf(v.w));
    ((ushort4*)Y)[i] = o;
  }
}

// transpose 1024x1024 fp32 W[i][j] -> bf16 Wt[j][i]
__global__ __launch_bounds__(256)
void transpose_cast(const float* __restrict__ W, unsigned short* __restrict__ Wt, int D) {
  __shared__ float s[32][33];
  int tx = threadIdx.x & 31, ty = threadIdx.x >> 5;  // 32x8
  int bx = blockIdx.x, by = blockIdx.y;
#pragma unroll
  for (int p = 0; p < 4; p++) {
    int r = by * 32 + ty + p * 8, c = bx * 32 + tx;
    s[ty + p * 8][tx] = W[(size_t)r * D + c];
  }
  __syncthreads();
#pragma unroll
  for (int p = 0; p < 4; p++) {
    int r = bx * 32 + ty + p * 8, c = by * 32 + tx;
    Wt[(size_t)r * D + c] = f2bf(s[tx][ty + p * 8]);
  }
}

// per-code squared norms (fp32), one wave per code row of 256
__global__ __launch_bounds__(256)
void code_norms(const float* __restrict__ cb, float* __restrict__ cn) {
  int row = blockIdx.x * 4 + (threadIdx.x >> 6);
  int lane = threadIdx.x & 63;
  float4 v = ((const float4*)(cb + (size_t)row * 256))[lane];
  float s = v.x * v.x + v.y * v.y + v.z * v.z + v.w * v.w;
#pragma unroll
  for (int off = 32; off > 0; off >>= 1) s += __shfl_down(s, off);
  if (lane == 0) cn[row] = s;
}

// ---------------------------------------------------------------------------
// GEMM: C[M,N] bf16 = relu(A[M,K]bf16 @ Bt[N,K]^T bf16 + bias)
// 128x128 tile, BK=128 (R14: halves barrier/drain count vs BK=64),
// DMA staging (global_load_lds w=16) + XOR swizzle. LDS 64KB, 2 blocks/CU.
__global__ __launch_bounds__(256, 2)
void gemm_bias_relu(const unsigned short* __restrict__ A, const unsigned short* __restrict__ Bt,
                    const float* __restrict__ bias, unsigned short* __restrict__ C,
                    int M, int N, int K) {
  __shared__ unsigned short As[128 * 128];
  __shared__ unsigned short Bs[128 * 128];
  const int t = threadIdx.x;
  const int wv = t >> 6, lane = t & 63;
  const int wm = wv >> 1, wn = wv & 1;
  const int quad = lane >> 4, l15 = lane & 15;
  const int row0 = blockIdx.y * 128, col0 = blockIdx.x * 128;
  const int rsub = lane >> 4;   // row within 4-row slab
  const int gran = lane & 15;   // 16B granule within 128-dim row

  f32x4 acc[4][4];
#pragma unroll
  for (int i = 0; i < 4; i++)
#pragma unroll
    for (int j = 0; j < 4; j++) acc[i][j] = (f32x4){0.f, 0.f, 0.f, 0.f};

  for (int k0 = 0; k0 < K; k0 += 128) {
#pragma unroll
    for (int j = 0; j < 8; j++) {
      int slab = j * 4 + wv;        // 32 slabs of 4 rows (1KB each)
      int row = slab * 4 + rsub;
      int g = gran ^ (row & 7);     // pre-swizzled global source granule
      gl2lds16(A + (size_t)(row0 + row) * K + k0 + g * 8, As + slab * 512);
      gl2lds16(Bt + (size_t)(col0 + row) * K + k0 + g * 8, Bs + slab * 512);
    }
    __syncthreads();
#pragma unroll
    for (int kk = 0; kk < 4; kk++) {
      bf16x8 af[4], bfr[4];
#pragma unroll
      for (int mt = 0; mt < 4; mt++) {
        int row = wm * 64 + mt * 16 + l15;
        af[mt] = *(const bf16x8*)(As + row * 128 + (((kk * 4 + quad) ^ (l15 & 7)) * 8));
      }
#pragma unroll
      for (int nt = 0; nt < 4; nt++) {
        int row = wn * 64 + nt * 16 + l15;
        bfr[nt] = *(const bf16x8*)(Bs + row * 128 + (((kk * 4 + quad) ^ (l15 & 7)) * 8));
      }
#pragma unroll
      for (int mt = 0; mt < 4; mt++)
#pragma unroll
        for (int nt = 0; nt < 4; nt++)
          acc[mt][nt] = __builtin_amdgcn_mfma_f32_16x16x32_bf16(af[mt], bfr[nt], acc[mt][nt], 0, 0, 0);
    }
    __syncthreads();
  }
#pragma unroll
  for (int mt = 0; mt < 4; mt++) {
#pragma unroll
    for (int nt = 0; nt < 4; nt++) {
      int col = col0 + wn * 64 + nt * 16 + l15;
      float b = bias[col];
#pragma unroll
      for (int r = 0; r < 4; r++) {
        int row = row0 + wm * 64 + mt * 16 + quad * 4 + r;
        float v = acc[mt][nt][r] + b;
        C[(size_t)row * N + col] = f2bf(v > 0.f ? v : 0.f);
      }
    }
  }
}

// ---------------------------------------------------------------------------
// LayerNorm over rows of 1024 (bf16 in); writes bf16 (obf) or fp32 (of32)
__global__ __launch_bounds__(256)
void ln_kernel(const unsigned short* __restrict__ X, const float* __restrict__ g,
               const float* __restrict__ b, unsigned short* __restrict__ obf,
               float* __restrict__ of32) {
  const int row = blockIdx.x, t = threadIdx.x;
  ushort4 u = ((const ushort4*)(X + (size_t)row * 1024))[t];
  float4 v = make_float4(bf2f(u.x), bf2f(u.y), bf2f(u.z), bf2f(u.w));
  float s = v.x + v.y + v.z + v.w;
  float ss = v.x * v.x + v.y * v.y + v.z * v.z + v.w * v.w;
#pragma unroll
  for (int off = 32; off > 0; off >>= 1) {
    s += __shfl_down(s, off);
    ss += __shfl_down(ss, off);
  }
  __shared__ float rs[4], rss[4];
  const int wave = t >> 6, lane = t & 63;
  if (lane == 0) { rs[wave] = s; rss[wave] = ss; }
  __syncthreads();
  float S = rs[0] + rs[1] + rs[2] + rs[3];
  float SS = rss[0] + rss[1] + rss[2] + rss[3];
  float m = S * (1.0f / 1024.0f);
  float var = SS * (1.0f / 1024.0f) - m * m;
  float rstd = 1.0f / sqrtf(var + 1e-5f);
  float4 gv = ((const float4*)g)[t];
  float4 bv = ((const float4*)b)[t];
  float4 o;
  o.x = (v.x - m) * rstd * gv.x + bv.x;
  o.y = (v.y - m) * rstd * gv.y + bv.y;
  o.z = (v.z - m) * rstd * gv.z + bv.z;
  o.w = (v.w - m) * rstd * gv.w + bv.w;
  if (obf) {
    ushort4 q = make_ushort4(f2bf(o.x), f2bf(o.y), f2bf(o.z), f2bf(o.w));
    ((ushort4*)(obf + (size_t)row * 1024))[t] = q;
  } else {
    ((float4*)(of32 + (size_t)row * 1024))[t] = o;
  }
}

// ---------------------------------------------------------------------------
// VQ distance+argmin+gather: Z[32768,256]bf16 vs Cb[8192,256]bf16.
// Block = 64 Z-rows x ALL 8192 codes (grid 512). Z register-resident zf[4][8].
// Chunk = 64 codes, ALL DMA-staged to LDS (dbuf 2x32KB, XOR swizzle,
// WAVE-PRIVATE slabs). NO barriers in main loop; per-wave vmcnt(0) at chunk
// top. R14: entry phase-stagger (s_sleep loop, hedged on blockIdx bits 8/3)
// to break the phase-lock between co-resident blocks' same-SIMD waves so
// stage and MFMA phases overlap across waves.
// Tail: gather cb rows for the block's 64 best indices, write qb bf16,
// histogram counts, per-block loss partial.
__global__ __launch_bounds__(256, 2)
void vq_dist(const unsigned short* __restrict__ Z, const unsigned short* __restrict__ Cb,
             const float* __restrict__ cnorm, const float* __restrict__ cbf,
             unsigned short* __restrict__ qb, int* __restrict__ counts,
             float* __restrict__ lpart) {
  __shared__ unsigned short Bs[2][64 * 256];  // 2 x 32KB
  __shared__ unsigned long long runmin[64];
  const int t = threadIdx.x;
  const int wv = t >> 6, lane = t & 63;
  const int quad = lane >> 4, l15 = lane & 15;
  const int row0 = blockIdx.x * 64;

  // phase-stagger: ~512cyc per sleep unit; hedge over plausible co-residency
  // pairings (stride-256 -> bit 8, Delta=3 units ~ half chunk; stride-8 ->
  // bit 3, Delta=1). Max one-time cost ~2k cyc (<1us), amortized over 128
  // chunks. Pure timing; no correctness impact.
  {
    int nsl = ((blockIdx.x >> 8) & 1) * 3 + ((blockIdx.x >> 3) & 1);
    for (int i = 0; i < nsl; i++) __builtin_amdgcn_s_sleep(8);
  }

  if (t < 64) runmin[t] = ~0ull;

  // Z fragments for this wave: rows mt*16+l15, K-step ks (8 bf16 each)
  bf16x8 zf[4][8];
#pragma unroll
  for (int mt = 0; mt < 4; mt++)
#pragma unroll
    for (int ks = 0; ks < 8; ks++)
      zf[mt][ks] = *(const bf16x8*)(Z + (size_t)(row0 + mt * 16 + l15) * 256 + ks * 32 + quad * 8);

  float msc[4][4];
  int mcd[4][4];
#pragma unroll
  for (int mt = 0; mt < 4; mt++)
#pragma unroll
    for (int r = 0; r < 4; r++) { msc[mt][r] = 3.4e38f; mcd[mt][r] = 0; }

  // LDS staging geometry: chunk ch codes [ch*64, ch*64+64) -> Bs[ch&1],
  // 32 slabs of 1KB (2 codes each). Wave wv stages slabs [8wv,8wv+8) ==
  // exactly slots [16wv,16wv+16) that it reads.
  const int dcode = lane >> 5;  // 0/1 within slab
  const int dgr = lane & 31;    // 16B granule within code row
  const int slot = wv * 16 + l15;
  const int rxor = l15 & 7;

  // precomputed swizzled ds-read offsets (ushort units), slot folded in
  unsigned swz[8];
#pragma unroll
  for (int ks = 0; ks < 8; ks++)
    swz[ks] = (unsigned)slot * 256 + (unsigned)(((ks * 4 + quad) ^ rxor) * 8);

  // ---- prologue: stage chunk 0 into Bs[0]; cnorm for chunk 0 ----
#pragma unroll
  for (int j = 0; j < 8; j++) {
    int slab = wv * 8 + j;
    int sl = slab * 2 + dcode;
    gl2lds16(Cb + (size_t)sl * 256 + ((dgr ^ (sl & 7)) * 8), &Bs[0][slab * 512]);
  }
  float cn_old = 3.4e38f;       // sentinel: ch=-1 deferred argmin never wins
  float cn_new = cnorm[slot];   // chunk 0's norm for this lane's code

  f32x4 pacc[4];
#pragma unroll
  for (int mt = 0; mt < 4; mt++) pacc[mt] = (f32x4){0.f, 0.f, 0.f, 0.f};

  for (int ch = 0; ch < 128; ch++) {
    const int cur = ch & 1;
    // wait for THIS wave's outstanding vmem (incl. its DMA for chunk ch,
    // issued a full chunk ago, and the cnorm load); lgkm/exp not waited.
    // Waves stay unsynchronized.
    __builtin_amdgcn_s_waitcnt(0x3F70);

    // prefetch DMA for chunk ch+1 (wrap: junk refill, never read)
    {
      const int cb2 = ((ch + 1) & 127) * 64;
#pragma unroll
      for (int j = 0; j < 8; j++) {
        int slab = wv * 8 + j;
        int sl = slab * 2 + dcode;
        gl2lds16(Cb + (size_t)(cb2 + sl) * 256 + ((dgr ^ (sl & 7)) * 8),
                 &Bs[cur ^ 1][slab * 512]);
      }
    }

    // issue ALL 8 ds_reads for this chunk (arrive ~12cy apart, consumed
    // ~19.4cy apart by the MFMA block -> no per-ks stalls)
    const unsigned short* bsc = &Bs[cur][0];
    bf16x8 lbuf[8];
#pragma unroll
    for (int ks = 0; ks < 8; ks++)
      lbuf[ks] = *(const bf16x8*)(bsc + swz[ks]);

    // deferred argmin for chunk ch-1 under the ds latency.
    // Per-lane visit order ascending in ch -> strict < keeps lowest index
    // (reference tie-break).
    {
      int code = (ch - 1) * 64 + slot;
#pragma unroll
      for (int mt = 0; mt < 4; mt++)
#pragma unroll
        for (int r = 0; r < 4; r++) {
          float sc = cn_old - 2.0f * pacc[mt][r];
          if (sc < msc[mt][r]) { msc[mt][r] = sc; mcd[mt][r] = code; }
        }
    }
    cn_old = cn_new;  // now holds chunk ch's norm (consumed next iteration)
    cn_new = cnorm[(((ch + 1) & 127) * 64) + slot];  // chunk ch+1's norm

    // MFMA block
#pragma unroll
    for (int ks = 0; ks < 8; ks++) {
      if (ks == 0) {
        const f32x4 z4 = (f32x4){0.f, 0.f, 0.f, 0.f};
#pragma unroll
        for (int mt = 0; mt < 4; mt++)
          pacc[mt] = __builtin_amdgcn_mfma_f32_16x16x32_bf16(zf[mt][0], lbuf[0], z4, 0, 0, 0);
      } else {
#pragma unroll
        for (int mt = 0; mt < 4; mt++)
          pacc[mt] = __builtin_amdgcn_mfma_f32_16x16x32_bf16(zf[mt][ks], lbuf[ks], pacc[mt], 0, 0, 0);
      }
    }
  }
  // final deferred argmin (chunk 127)
  {
    int code = 127 * 64 + slot;
#pragma unroll
    for (int mt = 0; mt < 4; mt++)
#pragma unroll
      for (int r = 0; r < 4; r++) {
        float sc = cn_old - 2.0f * pacc[mt][r];
        if (sc < msc[mt][r]) { msc[mt][r] = sc; mcd[mt][r] = code; }
      }
  }

  __syncthreads();  // runmin init visible; all waves done before merge
#pragma unroll
  for (int mt = 0; mt < 4; mt++) {
#pragma unroll
    for (int r = 0; r < 4; r++) {
      unsigned long long bp = packScore(msc[mt][r], mcd[mt][r]);
#pragma unroll
      for (int m = 1; m < 16; m <<= 1) {
        unsigned long long o = shflxor_u64(bp, m);
        bp = o < bp ? o : bp;
      }
      if (l15 == 0) atomicMin(&runmin[mt * 16 + quad * 4 + r], bp);
    }
  }
  __syncthreads();

  // ---- tail: gather + qb write + loss partial + histogram ----
  // wave wv handles local rows [16wv, 16wv+16); per row 64 lanes x float4.
  float lp = 0.f;
#pragma unroll 4
  for (int rr = 0; rr < 16; rr++) {
    const int row = wv * 16 + rr;
    const int idx = (int)(runmin[row] & 0xFFFFFFFFull);
    float4 c = ((const float4*)(cbf + (size_t)idx * 256))[lane];
    ushort4 q = make_ushort4(f2bf(c.x), f2bf(c.y), f2bf(c.z), f2bf(c.w));
    ((ushort4*)(qb + (size_t)(row0 + row) * 256))[lane] = q;
    ushort4 z = ((const ushort4*)(Z + (size_t)(row0 + row) * 256))[lane];
    float dx = c.x - bf2f(z.x), dy = c.y - bf2f(z.y);
    float dz = c.z - bf2f(z.z), dw = c.w - bf2f(z.w);
    lp += dx * dx + dy * dy + dz * dz + dw * dw;
  }
  // one histogram add per row (rows are block-exclusive)
  if (t < 64) atomicAdd(&counts[(int)(runmin[t] & 0xFFFFFFFFull)], 1);
  // block loss reduction
#pragma unroll
  for (int off = 32; off > 0; off >>= 1) lp += __shfl_down(lp, off);
  __shared__ float sp[4];
  if (lane == 0) sp[wv] = lp;
  __syncthreads();
  if (t == 0) lpart[blockIdx.x] = sp[0] + sp[1] + sp[2] + sp[3];
}

// loss + perplexity scalars (lpart = 512 block partials)
__global__ __launch_bounds__(256)
void finalize(const int* __restrict__ counts, const float* __restrict__ lpart,
              float* __restrict__ out2) {
  const int t = threadIdx.x;
  double h = 0.0, l = 0.0;
  for (int i = t; i < 8192; i += 256) {
    double pr = (double)counts[i] * (1.0 / 32768.0);
    h += pr * log(pr + 1e-10);
  }
  for (int i = t; i < 512; i += 256) l += (double)lpart[i];
  __shared__ double sh[256], sl[256];
  sh[t] = h;
  sl[t] = l;
  __syncthreads();
  for (int w = 128; w > 0; w >>= 1) {
    if (t < w) { sh[t] += sh[t + w]; sl[t] += sl[t + w]; }
    __syncthreads();
  }
  if (t == 0) {
    out2[0] = (float)(1.25 * sl[0] * (1.0 / 8388608.0));
    out2[1] = (float)exp(-sh[0]);
  }
}

// ---------------------------------------------------------------------------
extern "C" void kernel_launch(void* const* d_in, const int* in_sizes, int n_in,
                              void* d_out, int out_size, void* d_ws, size_t ws_size,
                              hipStream_t stream) {
  const float* x = (const float*)d_in[0];
  const float* We1 = (const float*)d_in[1];
  const float* be1 = (const float*)d_in[2];
  const float* ge1 = (const float*)d_in[3];
  const float* bne1 = (const float*)d_in[4];
  const float* We2 = (const float*)d_in[5];
  const float* be2 = (const float*)d_in[6];
  const float* ge2 = (const float*)d_in[7];
  const float* bne2 = (const float*)d_in[8];
  const float* Wd1 = (const float*)d_in[9];
  const float* bd1 = (const float*)d_in[10];
  const float* gd1 = (const float*)d_in[11];
  const float* bnd1 = (const float*)d_in[12];
  const float* Wd2 = (const float*)d_in[13];
  const float* bd2 = (const float*)d_in[14];
  const float* gd2 = (const float*)d_in[15];
  const float* bnd2 = (const float*)d_in[16];
  const float* codebook = (const float*)d_in[17];
  float* out = (float*)d_out;

  char* w = (char*)d_ws;
  auto alloc = [&](size_t bytes) -> char* {
    char* p = w;
    w += (bytes + 255) & ~(size_t)255;
    return p;
  };
  unsigned short* xb = (unsigned short*)alloc((size_t)8192 * 1024 * 2);
  unsigned short* wt0 = (unsigned short*)alloc((size_t)1024 * 1024 * 2);
  unsigned short* wt1 = (unsigned short*)alloc((size_t)1024 * 1024 * 2);
  unsigned short* wt2 = (unsigned short*)alloc((size_t)1024 * 1024 * 2);
  unsigned short* wt3 = (unsigned short*)alloc((size_t)1024 * 1024 * 2);
  unsigned short* cbb = (unsigned short*)alloc((size_t)8192 * 256 * 2);
  float* cnorm = (float*)alloc((size_t)8192 * 4);
  unsigned short* act = (unsigned short*)alloc((size_t)8192 * 1024 * 2);
  unsigned short* yb = (unsigned short*)alloc((size_t)8192 * 1024 * 2);
  unsigned short* zb = (unsigned short*)alloc((size_t)8192 * 1024 * 2);
  unsigned short* qb = (unsigned short*)alloc((size_t)8192 * 1024 * 2);
  int* counts = (int*)alloc((size_t)8192 * 4);
  float* lpart = (float*)alloc((size_t)512 * 4);

  hipMemsetAsync(counts, 0, (size_t)8192 * 4, stream);

  cast_bf16<<<(2097152 + 255) / 256, 256, 0, stream>>>(x, xb, 2097152);
  dim3 tg(32, 32);
  transpose_cast<<<tg, 256, 0, stream>>>(We1, wt0, 1024);
  transpose_cast<<<tg, 256, 0, stream>>>(We2, wt1, 1024);
  transpose_cast<<<tg, 256, 0, stream>>>(Wd1, wt2, 1024);
  transpose_cast<<<tg, 256, 0, stream>>>(Wd2, wt3, 1024);
  cast_bf16<<<(524288 + 255) / 256, 256, 0, stream>>>(codebook, cbb, 524288);
  code_norms<<<2048, 256, 0, stream>>>(codebook, cnorm);

  dim3 gg(8, 64);
  // encoder
  gemm_bias_relu<<<gg, 256, 0, stream>>>(xb, wt0, be1, act, 8192, 1024, 1024);
  ln_kernel<<<8192, 256, 0, stream>>>(act, ge1, bne1, yb, nullptr);
  gemm_bias_relu<<<gg, 256, 0, stream>>>(yb, wt1, be2, act, 8192, 1024, 1024);
  ln_kernel<<<8192, 256, 0, stream>>>(act, ge2, bne2, zb, nullptr);
  // VQ (distance + argmin + gather + histogram + loss partial, fused)
  vq_dist<<<512, 256, 0, stream>>>(zb, cbb, cnorm, codebook, qb, counts, lpart);
  // decoder
  gemm_bias_relu<<<gg, 256, 0, stream>>>(qb, wt2, bd1, act, 8192, 1024, 1024);
  ln_kernel<<<8192, 256, 0, stream>>>(act, gd1, bnd1, yb, nullptr);
  gemm_bias_relu<<<gg, 256, 0, stream>>>(yb, wt3, bd2, act, 8192, 1024, 1024);
  ln_kernel<<<8192, 256, 0, stream>>>(act, gd2, bnd2, nullptr, out);

  finalize<<<1, 256, 0, stream>>>(counts, lpart, out + 8388608);
}

// Round 7
// 443.905 us; speedup vs baseline: 1.0309x; 1.0309x over previous
//
#include <hip/hip_runtime.h>
#include <stdint.h>

// ---------------------------------------------------------------------------
// VQ-VAE layer, all-bf16 MFMA pipeline.
// R14 -> R15: stagger (vq) and BK=128 (GEMM) both neutral -- reverted.
// Re-audit: non-vq time ~280us, of which 4 GEMMs ~240us (~286 TF each) --
// GEMM is now the bigger pool. Root causes found:
//  (a) grid (8,64): linear ID round-robins XCDs -> XCD x gets column-stripe
//      bx==x across ALL row panels -> every XCD streams the ENTIRE 16MB A
//      through its 4MB L2 -> 128MB HBM A-traffic per GEMM.
//  (b) stage->sync->compute exposes full memory latency each K-step.
// Fixes: (1) XCD-chunked bijective remap (nl=(lin&7)*64+lin>>3): XCD owns
// 8 row-panels x all cols -> per-XCD working set ~4MB = L2-resident; A HBM
// 128->16MB. (2) double-buffered staging (2x64KB LDS, 2 blocks/CU): DMA for
// k+1 issued BEFORE compute(k) -> barrier drain lands ~1200cyc later.
// vq_dist: exact R13 structure (fused gather tail, no stagger, no setprio).
// ---------------------------------------------------------------------------

typedef short bf16x8 __attribute__((ext_vector_type(8)));
typedef float f32x4 __attribute__((ext_vector_type(4)));

__device__ __forceinline__ void gl2lds16(const void* g, void* l) {
  __builtin_amdgcn_global_load_lds(
      (const __attribute__((address_space(1))) void*)g,
      (__attribute__((address_space(3))) void*)l, 16, 0, 0);
}

__device__ __forceinline__ float bf2f(unsigned short u) {
  return __uint_as_float(((unsigned)u) << 16);
}
__device__ __forceinline__ unsigned short f2bf(float f) {
  unsigned x = __float_as_uint(f);
  unsigned r = (x + 0x7fffu + ((x >> 16) & 1u)) >> 16;  // RNE
  return (unsigned short)r;
}
__device__ __forceinline__ unsigned long long packScore(float s, int code) {
  unsigned u = __float_as_uint(s);
  u = (u & 0x80000000u) ? ~u : (u | 0x80000000u);  // monotone map f32 -> u32
  return ((unsigned long long)u << 32) | (unsigned)code;
}
__device__ __forceinline__ unsigned long long shflxor_u64(unsigned long long v, int m) {
  union { unsigned long long u; int i[2]; } a;
  a.u = v;
  a.i[0] = __shfl_xor(a.i[0], m);
  a.i[1] = __shfl_xor(a.i[1], m);
  return a.u;
}

// ---------------------------------------------------------------------------
// cast fp32 -> bf16 (vectorized, n4 = count/4)
__global__ __launch_bounds__(256)
void cast_bf16(const float* __restrict__ X, unsigned short* __restrict__ Y, int n4) {
  int i = blockIdx.x * 256 + threadIdx.x;
  if (i < n4) {
    float4 v = ((const float4*)X)[i];
    ushort4 o = make_ushort4(f2bf(v.x), f2bf(v.y), f2bf(v.z), f2bf(v.w));
    ((ushort4*)Y)[i] = o;
  }
}

// transpose 1024x1024 fp32 W[i][j] -> bf16 Wt[j][i]
__global__ __launch_bounds__(256)
void transpose_cast(const float* __restrict__ W, unsigned short* __restrict__ Wt, int D) {
  __shared__ float s[32][33];
  int tx = threadIdx.x & 31, ty = threadIdx.x >> 5;  // 32x8
  int bx = blockIdx.x, by = blockIdx.y;
#pragma unroll
  for (int p = 0; p < 4; p++) {
    int r = by * 32 + ty + p * 8, c = bx * 32 + tx;
    s[ty + p * 8][tx] = W[(size_t)r * D + c];
  }
  __syncthreads();
#pragma unroll
  for (int p = 0; p < 4; p++) {
    int r = bx * 32 + ty + p * 8, c = by * 32 + tx;
    Wt[(size_t)r * D + c] = f2bf(s[tx][ty + p * 8]);
  }
}

// per-code squared norms (fp32), one wave per code row of 256
__global__ __launch_bounds__(256)
void code_norms(const float* __restrict__ cb, float* __restrict__ cn) {
  int row = blockIdx.x * 4 + (threadIdx.x >> 6);
  int lane = threadIdx.x & 63;
  float4 v = ((const float4*)(cb + (size_t)row * 256))[lane];
  float s = v.x * v.x + v.y * v.y + v.z * v.z + v.w * v.w;
#pragma unroll
  for (int off = 32; off > 0; off >>= 1) s += __shfl_down(s, off);
  if (lane == 0) cn[row] = s;
}

// ---------------------------------------------------------------------------
// GEMM: C[M,N] bf16 = relu(A[M,K]bf16 @ Bt[N,K]^T bf16 + bias)
// 128x128 tile, BK=64, double-buffered DMA staging + XOR swizzle,
// XCD-chunked block remap (each XCD owns 8 contiguous row-panels x all cols
// -> per-XCD working set ~4MB, L2-resident).
__global__ __launch_bounds__(256, 2)
void gemm_bias_relu(const unsigned short* __restrict__ A, const unsigned short* __restrict__ Bt,
                    const float* __restrict__ bias, unsigned short* __restrict__ C,
                    int M, int N, int K) {
  __shared__ unsigned short As[2][128 * 64];
  __shared__ unsigned short Bs[2][128 * 64];
  const int t = threadIdx.x;
  const int wv = t >> 6, lane = t & 63;
  const int wm = wv >> 1, wn = wv & 1;
  const int quad = lane >> 4, l15 = lane & 15;

  // XCD-chunked bijective remap: consecutive dispatch IDs round-robin the 8
  // XCDs; remap so XCD x runs linear IDs [x*cpx,(x+1)*cpx) = contiguous
  // row-panel range. Requires nwg % 8 == 0 (512 here).
  const int lin = blockIdx.y * gridDim.x + blockIdx.x;
  const int cpx = (gridDim.x * gridDim.y) >> 3;
  const int nl = (lin & 7) * cpx + (lin >> 3);
  const int bx = nl % gridDim.x, by = nl / gridDim.x;
  const int row0 = by * 128, col0 = bx * 128;

  const int rsub = lane >> 3;            // row within 8-row slab
  const int dchunk = (lane & 7) ^ rsub;  // xor-swizzled data chunk to fetch

  f32x4 acc[4][4];
#pragma unroll
  for (int i = 0; i < 4; i++)
#pragma unroll
    for (int j = 0; j < 4; j++) acc[i][j] = (f32x4){0.f, 0.f, 0.f, 0.f};

  // prologue: stage k=0 into buffer 0
#pragma unroll
  for (int j = 0; j < 4; j++) {
    int slab = j * 4 + wv;
    int row = slab * 8 + rsub;
    gl2lds16(A + (size_t)(row0 + row) * K + dchunk * 8, &As[0][slab * 512]);
    gl2lds16(Bt + (size_t)(col0 + row) * K + dchunk * 8, &Bs[0][slab * 512]);
  }
  __syncthreads();

  int cur = 0;
  for (int k0 = 0; k0 < K; k0 += 64) {
    // prefetch next K-step into the other buffer BEFORE compute: the
    // end-of-step barrier's vmcnt(0) drain lands ~1200cyc after issue.
    if (k0 + 64 < K) {
#pragma unroll
      for (int j = 0; j < 4; j++) {
        int slab = j * 4 + wv;
        int row = slab * 8 + rsub;
        gl2lds16(A + (size_t)(row0 + row) * K + (k0 + 64) + dchunk * 8,
                 &As[cur ^ 1][slab * 512]);
        gl2lds16(Bt + (size_t)(col0 + row) * K + (k0 + 64) + dchunk * 8,
                 &Bs[cur ^ 1][slab * 512]);
      }
    }
#pragma unroll
    for (int kk = 0; kk < 2; kk++) {
      bf16x8 af[4], bfr[4];
#pragma unroll
      for (int mt = 0; mt < 4; mt++) {
        int row = wm * 64 + mt * 16 + l15;
        af[mt] = *(const bf16x8*)(&As[cur][row * 64 + (((kk * 4 + quad) ^ (l15 & 7)) * 8)]);
      }
#pragma unroll
      for (int nt = 0; nt < 4; nt++) {
        int row = wn * 64 + nt * 16 + l15;
        bfr[nt] = *(const bf16x8*)(&Bs[cur][row * 64 + (((kk * 4 + quad) ^ (l15 & 7)) * 8)]);
      }
#pragma unroll
      for (int mt = 0; mt < 4; mt++)
#pragma unroll
        for (int nt = 0; nt < 4; nt++)
          acc[mt][nt] = __builtin_amdgcn_mfma_f32_16x16x32_bf16(af[mt], bfr[nt], acc[mt][nt], 0, 0, 0);
    }
    __syncthreads();
    cur ^= 1;
  }
#pragma unroll
  for (int mt = 0; mt < 4; mt++) {
#pragma unroll
    for (int nt = 0; nt < 4; nt++) {
      int col = col0 + wn * 64 + nt * 16 + l15;
      float b = bias[col];
#pragma unroll
      for (int r = 0; r < 4; r++) {
        int row = row0 + wm * 64 + mt * 16 + quad * 4 + r;
        float v = acc[mt][nt][r] + b;
        C[(size_t)row * N + col] = f2bf(v > 0.f ? v : 0.f);
      }
    }
  }
}

// ---------------------------------------------------------------------------
// LayerNorm over rows of 1024 (bf16 in); writes bf16 (obf) or fp32 (of32)
__global__ __launch_bounds__(256)
void ln_kernel(const unsigned short* __restrict__ X, const float* __restrict__ g,
               const float* __restrict__ b, unsigned short* __restrict__ obf,
               float* __restrict__ of32) {
  const int row = blockIdx.x, t = threadIdx.x;
  ushort4 u = ((const ushort4*)(X + (size_t)row * 1024))[t];
  float4 v = make_float4(bf2f(u.x), bf2f(u.y), bf2f(u.z), bf2f(u.w));
  float s = v.x + v.y + v.z + v.w;
  float ss = v.x * v.x + v.y * v.y + v.z * v.z + v.w * v.w;
#pragma unroll
  for (int off = 32; off > 0; off >>= 1) {
    s += __shfl_down(s, off);
    ss += __shfl_down(ss, off);
  }
  __shared__ float rs[4], rss[4];
  const int wave = t >> 6, lane = t & 63;
  if (lane == 0) { rs[wave] = s; rss[wave] = ss; }
  __syncthreads();
  float S = rs[0] + rs[1] + rs[2] + rs[3];
  float SS = rss[0] + rss[1] + rss[2] + rss[3];
  float m = S * (1.0f / 1024.0f);
  float var = SS * (1.0f / 1024.0f) - m * m;
  float rstd = 1.0f / sqrtf(var + 1e-5f);
  float4 gv = ((const float4*)g)[t];
  float4 bv = ((const float4*)b)[t];
  float4 o;
  o.x = (v.x - m) * rstd * gv.x + bv.x;
  o.y = (v.y - m) * rstd * gv.y + bv.y;
  o.z = (v.z - m) * rstd * gv.z + bv.z;
  o.w = (v.w - m) * rstd * gv.w + bv.w;
  if (obf) {
    ushort4 q = make_ushort4(f2bf(o.x), f2bf(o.y), f2bf(o.z), f2bf(o.w));
    ((ushort4*)(obf + (size_t)row * 1024))[t] = q;
  } else {
    ((float4*)(of32 + (size_t)row * 1024))[t] = o;
  }
}

// ---------------------------------------------------------------------------
// VQ distance+argmin+gather: Z[32768,256]bf16 vs Cb[8192,256]bf16.
// Block = 64 Z-rows x ALL 8192 codes (grid 512). Z register-resident zf[4][8].
// Chunk = 64 codes, ALL DMA-staged to LDS (dbuf 2x32KB, XOR swizzle,
// WAVE-PRIVATE slabs). NO barriers in main loop; per-wave vmcnt(0) at chunk
// top. Exact R13 structure (173us): all-8 ds_reads at chunk top, deferred
// argmin under ds latency, pure 32-MFMA block, fused gather tail.
__global__ __launch_bounds__(256, 2)
void vq_dist(const unsigned short* __restrict__ Z, const unsigned short* __restrict__ Cb,
             const float* __restrict__ cnorm, const float* __restrict__ cbf,
             unsigned short* __restrict__ qb, int* __restrict__ counts,
             float* __restrict__ lpart) {
  __shared__ unsigned short Bs[2][64 * 256];  // 2 x 32KB
  __shared__ unsigned long long runmin[64];
  const int t = threadIdx.x;
  const int wv = t >> 6, lane = t & 63;
  const int quad = lane >> 4, l15 = lane & 15;
  const int row0 = blockIdx.x * 64;

  if (t < 64) runmin[t] = ~0ull;

  // Z fragments for this wave: rows mt*16+l15, K-step ks (8 bf16 each)
  bf16x8 zf[4][8];
#pragma unroll
  for (int mt = 0; mt < 4; mt++)
#pragma unroll
    for (int ks = 0; ks < 8; ks++)
      zf[mt][ks] = *(const bf16x8*)(Z + (size_t)(row0 + mt * 16 + l15) * 256 + ks * 32 + quad * 8);

  float msc[4][4];
  int mcd[4][4];
#pragma unroll
  for (int mt = 0; mt < 4; mt++)
#pragma unroll
    for (int r = 0; r < 4; r++) { msc[mt][r] = 3.4e38f; mcd[mt][r] = 0; }

  const int dcode = lane >> 5;  // 0/1 within slab
  const int dgr = lane & 31;    // 16B granule within code row
  const int slot = wv * 16 + l15;
  const int rxor = l15 & 7;

  // precomputed swizzled ds-read offsets (ushort units), slot folded in
  unsigned swz[8];
#pragma unroll
  for (int ks = 0; ks < 8; ks++)
    swz[ks] = (unsigned)slot * 256 + (unsigned)(((ks * 4 + quad) ^ rxor) * 8);

  // ---- prologue: stage chunk 0 into Bs[0]; cnorm for chunk 0 ----
#pragma unroll
  for (int j = 0; j < 8; j++) {
    int slab = wv * 8 + j;
    int sl = slab * 2 + dcode;
    gl2lds16(Cb + (size_t)sl * 256 + ((dgr ^ (sl & 7)) * 8), &Bs[0][slab * 512]);
  }
  float cn_old = 3.4e38f;       // sentinel: ch=-1 deferred argmin never wins
  float cn_new = cnorm[slot];   // chunk 0's norm for this lane's code

  f32x4 pacc[4];
#pragma unroll
  for (int mt = 0; mt < 4; mt++) pacc[mt] = (f32x4){0.f, 0.f, 0.f, 0.f};

  for (int ch = 0; ch < 128; ch++) {
    const int cur = ch & 1;
    // wait for THIS wave's outstanding vmem (incl. its DMA for chunk ch,
    // issued a full chunk ago, and the cnorm load); lgkm/exp not waited.
    __builtin_amdgcn_s_waitcnt(0x3F70);

    // prefetch DMA for chunk ch+1 (wrap: junk refill, never read)
    {
      const int cb2 = ((ch + 1) & 127) * 64;
#pragma unroll
      for (int j = 0; j < 8; j++) {
        int slab = wv * 8 + j;
        int sl = slab * 2 + dcode;
        gl2lds16(Cb + (size_t)(cb2 + sl) * 256 + ((dgr ^ (sl & 7)) * 8),
                 &Bs[cur ^ 1][slab * 512]);
      }
    }

    // issue ALL 8 ds_reads for this chunk
    const unsigned short* bsc = &Bs[cur][0];
    bf16x8 lbuf[8];
#pragma unroll
    for (int ks = 0; ks < 8; ks++)
      lbuf[ks] = *(const bf16x8*)(bsc + swz[ks]);

    // deferred argmin for chunk ch-1 under the ds latency.
    // Per-lane visit order ascending in ch -> strict < keeps lowest index.
    {
      int code = (ch - 1) * 64 + slot;
#pragma unroll
      for (int mt = 0; mt < 4; mt++)
#pragma unroll
        for (int r = 0; r < 4; r++) {
          float sc = cn_old - 2.0f * pacc[mt][r];
          if (sc < msc[mt][r]) { msc[mt][r] = sc; mcd[mt][r] = code; }
        }
    }
    cn_old = cn_new;
    cn_new = cnorm[(((ch + 1) & 127) * 64) + slot];

    // MFMA block
#pragma unroll
    for (int ks = 0; ks < 8; ks++) {
      if (ks == 0) {
        const f32x4 z4 = (f32x4){0.f, 0.f, 0.f, 0.f};
#pragma unroll
        for (int mt = 0; mt < 4; mt++)
          pacc[mt] = __builtin_amdgcn_mfma_f32_16x16x32_bf16(zf[mt][0], lbuf[0], z4, 0, 0, 0);
      } else {
#pragma unroll
        for (int mt = 0; mt < 4; mt++)
          pacc[mt] = __builtin_amdgcn_mfma_f32_16x16x32_bf16(zf[mt][ks], lbuf[ks], pacc[mt], 0, 0, 0);
      }
    }
  }
  // final deferred argmin (chunk 127)
  {
    int code = 127 * 64 + slot;
#pragma unroll
    for (int mt = 0; mt < 4; mt++)
#pragma unroll
      for (int r = 0; r < 4; r++) {
        float sc = cn_old - 2.0f * pacc[mt][r];
        if (sc < msc[mt][r]) { msc[mt][r] = sc; mcd[mt][r] = code; }
      }
  }

  __syncthreads();  // runmin init visible; all waves done before merge
#pragma unroll
  for (int mt = 0; mt < 4; mt++) {
#pragma unroll
    for (int r = 0; r < 4; r++) {
      unsigned long long bp = packScore(msc[mt][r], mcd[mt][r]);
#pragma unroll
      for (int m = 1; m < 16; m <<= 1) {
        unsigned long long o = shflxor_u64(bp, m);
        bp = o < bp ? o : bp;
      }
      if (l15 == 0) atomicMin(&runmin[mt * 16 + quad * 4 + r], bp);
    }
  }
  __syncthreads();

  // ---- tail: gather + qb write + loss partial + histogram ----
  float lp = 0.f;
#pragma unroll 4
  for (int rr = 0; rr < 16; rr++) {
    const int row = wv * 16 + rr;
    const int idx = (int)(runmin[row] & 0xFFFFFFFFull);
    float4 c = ((const float4*)(cbf + (size_t)idx * 256))[lane];
    ushort4 q = make_ushort4(f2bf(c.x), f2bf(c.y), f2bf(c.z), f2bf(c.w));
    ((ushort4*)(qb + (size_t)(row0 + row) * 256))[lane] = q;
    ushort4 z = ((const ushort4*)(Z + (size_t)(row0 + row) * 256))[lane];
    float dx = c.x - bf2f(z.x), dy = c.y - bf2f(z.y);
    float dz = c.z - bf2f(z.z), dw = c.w - bf2f(z.w);
    lp += dx * dx + dy * dy + dz * dz + dw * dw;
  }
  if (t < 64) atomicAdd(&counts[(int)(runmin[t] & 0xFFFFFFFFull)], 1);
#pragma unroll
  for (int off = 32; off > 0; off >>= 1) lp += __shfl_down(lp, off);
  __shared__ float sp[4];
  if (lane == 0) sp[wv] = lp;
  __syncthreads();
  if (t == 0) lpart[blockIdx.x] = sp[0] + sp[1] + sp[2] + sp[3];
}

// loss + perplexity scalars (lpart = 512 block partials)
__global__ __launch_bounds__(256)
void finalize(const int* __restrict__ counts, const float* __restrict__ lpart,
              float* __restrict__ out2) {
  const int t = threadIdx.x;
  double h = 0.0, l = 0.0;
  for (int i = t; i < 8192; i += 256) {
    double pr = (double)counts[i] * (1.0 / 32768.0);
    h += pr * log(pr + 1e-10);
  }
  for (int i = t; i < 512; i += 256) l += (double)lpart[i];
  __shared__ double sh[256], sl[256];
  sh[t] = h;
  sl[t] = l;
  __syncthreads();
  for (int w = 128; w > 0; w >>= 1) {
    if (t < w) { sh[t] += sh[t + w]; sl[t] += sl[t + w]; }
    __syncthreads();
  }
  if (t == 0) {
    out2[0] = (float)(1.25 * sl[0] * (1.0 / 8388608.0));
    out2[1] = (float)exp(-sh[0]);
  }
}

// ---------------------------------------------------------------------------
extern "C" void kernel_launch(void* const* d_in, const int* in_sizes, int n_in,
                              void* d_out, int out_size, void* d_ws, size_t ws_size,
                              hipStream_t stream) {
  const float* x = (const float*)d_in[0];
  const float* We1 = (const float*)d_in[1];
  const float* be1 = (const float*)d_in[2];
  const float* ge1 = (const float*)d_in[3];
  const float* bne1 = (const float*)d_in[4];
  const float* We2 = (const float*)d_in[5];
  const float* be2 = (const float*)d_in[6];
  const float* ge2 = (const float*)d_in[7];
  const float* bne2 = (const float*)d_in[8];
  const float* Wd1 = (const float*)d_in[9];
  const float* bd1 = (const float*)d_in[10];
  const float* gd1 = (const float*)d_in[11];
  const float* bnd1 = (const float*)d_in[12];
  const float* Wd2 = (const float*)d_in[13];
  const float* bd2 = (const float*)d_in[14];
  const float* gd2 = (const float*)d_in[15];
  const float* bnd2 = (const float*)d_in[16];
  const float* codebook = (const float*)d_in[17];
  float* out = (float*)d_out;

  char* w = (char*)d_ws;
  auto alloc = [&](size_t bytes) -> char* {
    char* p = w;
    w += (bytes + 255) & ~(size_t)255;
    return p;
  };
  unsigned short* xb = (unsigned short*)alloc((size_t)8192 * 1024 * 2);
  unsigned short* wt0 = (unsigned short*)alloc((size_t)1024 * 1024 * 2);
  unsigned short* wt1 = (unsigned short*)alloc((size_t)1024 * 1024 * 2);
  unsigned short* wt2 = (unsigned short*)alloc((size_t)1024 * 1024 * 2);
  unsigned short* wt3 = (unsigned short*)alloc((size_t)1024 * 1024 * 2);
  unsigned short* cbb = (unsigned short*)alloc((size_t)8192 * 256 * 2);
  float* cnorm = (float*)alloc((size_t)8192 * 4);
  unsigned short* act = (unsigned short*)alloc((size_t)8192 * 1024 * 2);
  unsigned short* yb = (unsigned short*)alloc((size_t)8192 * 1024 * 2);
  unsigned short* zb = (unsigned short*)alloc((size_t)8192 * 1024 * 2);
  unsigned short* qb = (unsigned short*)alloc((size_t)8192 * 1024 * 2);
  int* counts = (int*)alloc((size_t)8192 * 4);
  float* lpart = (float*)alloc((size_t)512 * 4);

  hipMemsetAsync(counts, 0, (size_t)8192 * 4, stream);

  cast_bf16<<<(2097152 + 255) / 256, 256, 0, stream>>>(x, xb, 2097152);
  dim3 tg(32, 32);
  transpose_cast<<<tg, 256, 0, stream>>>(We1, wt0, 1024);
  transpose_cast<<<tg, 256, 0, stream>>>(We2, wt1, 1024);
  transpose_cast<<<tg, 256, 0, stream>>>(Wd1, wt2, 1024);
  transpose_cast<<<tg, 256, 0, stream>>>(Wd2, wt3, 1024);
  cast_bf16<<<(524288 + 255) / 256, 256, 0, stream>>>(codebook, cbb, 524288);
  code_norms<<<2048, 256, 0, stream>>>(codebook, cnorm);

  dim3 gg(8, 64);
  // encoder
  gemm_bias_relu<<<gg, 256, 0, stream>>>(xb, wt0, be1, act, 8192, 1024, 1024);
  ln_kernel<<<8192, 256, 0, stream>>>(act, ge1, bne1, yb, nullptr);
  gemm_bias_relu<<<gg, 256, 0, stream>>>(yb, wt1, be2, act, 8192, 1024, 1024);
  ln_kernel<<<8192, 256, 0, stream>>>(act, ge2, bne2, zb, nullptr);
  // VQ (distance + argmin + gather + histogram + loss partial, fused)
  vq_dist<<<512, 256, 0, stream>>>(zb, cbb, cnorm, codebook, qb, counts, lpart);
  // decoder
  gemm_bias_relu<<<gg, 256, 0, stream>>>(qb, wt2, bd1, act, 8192, 1024, 1024);
  ln_kernel<<<8192, 256, 0, stream>>>(act, gd1, bnd1, yb, nullptr);
  gemm_bias_relu<<<gg, 256, 0, stream>>>(yb, wt3, bd2, act, 8192, 1024, 1024);
  ln_kernel<<<8192, 256, 0, stream>>>(act, gd2, bnd2, nullptr, out);

  finalize<<<1, 256, 0, stream>>>(counts, lpart, out + 8388608);
}